// Round 17
// baseline (107.357 us; speedup 1.0000x reference)
//
#include <hip/hip_runtime.h>

typedef __attribute__((ext_vector_type(8))) _Float16 f16x8;  // 8 f16 in 4 VGPRs
typedef __attribute__((ext_vector_type(2))) __fp16 fp16x2r;  // cvt_pkrtz return type
typedef __attribute__((ext_vector_type(4))) float f32x4;
typedef __attribute__((ext_vector_type(2))) float f32x2;

#define BLK   256
#define NWAVE 4
#define NPT   16      // points per wave-tile
#define MAXB  2048

union F16U  { uint4 u; f16x8 v; };
union PairU { float4 f4; f32x2 p[2]; };   // view float4 as two aligned f32 pairs
union AccU  { f32x4 v; f32x2 p[2]; };     // view MFMA acc as two aligned pairs

// ---- packed dual-FP32 via native vector ops (compiler selects v_pk_*). ----
__device__ __forceinline__ f32x2 pk_fma(f32x2 a, f32x2 b, f32x2 c) {
    return __builtin_elementwise_fma(a, b, c);
}
__device__ __forceinline__ f32x2 pk_mul(f32x2 a, f32x2 b) { return a * b; }
__device__ __forceinline__ f32x2 pk_add(f32x2 a, f32x2 b) { return a + b; }

// Rational tanh pair: Pade[7/6] on x clamped to [-6,6].
//   tanh(x) ~ x(135135 + 17325 t + 378 t^2 + t^3) / (135135 + 62370 t + 3150 t^2 + 28 t^3)
// Max abs err ~4e-4 (at |x|=6); |x|>6 clamps (true tanh within 1.2e-5 of +-1).
// ONE trans op (rcp) per element vs the exp2+rcp form's TWO SERIAL trans —
// r13/r16 counters put trans at ~60% of VALU busy and twice on every chain.
__device__ __forceinline__ f32x2 tanh2r(f32x2 a) {
    const f32x2 six2    = {6.0f, 6.0f};
    const f32x2 nsix2   = {-6.0f, -6.0f};
    const f32x2 c378    = {378.0f, 378.0f};
    const f32x2 c17325  = {17325.0f, 17325.0f};
    const f32x2 c135135 = {135135.0f, 135135.0f};
    const f32x2 c28     = {28.0f, 28.0f};
    const f32x2 c3150   = {3150.0f, 3150.0f};
    const f32x2 c62370  = {62370.0f, 62370.0f};
    f32x2 xc = __builtin_elementwise_min(__builtin_elementwise_max(a, nsix2), six2);
    const f32x2 t = pk_mul(xc, xc);
    f32x2 n = pk_add(t, c378);
    n = pk_fma(n, t, c17325);
    n = pk_fma(n, t, c135135);
    n = pk_mul(n, xc);
    f32x2 d = pk_fma(c28, t, c3150);
    d = pk_fma(d, t, c62370);
    d = pk_fma(d, t, c135135);
    f32x2 r;
    r.x = __builtin_amdgcn_rcpf(d.x);
    r.y = __builtin_amdgcn_rcpf(d.y);
    return pk_mul(n, r);
}

// Two f32 -> packed f16x2 in one v_cvt_pkrtz_f16_f32.
__device__ __forceinline__ unsigned int pkh(float a, float b) {
    union { fp16x2r h; unsigned int u; } t;
    t.h = __builtin_amdgcn_cvt_pkrtz(a, b);
    return t.u;
}

__device__ __forceinline__ f16x8 pack8h(const float* v) {
    F16U r;
    r.u = make_uint4(pkh(v[0], v[1]), pkh(v[2], v[3]),
                     pkh(v[4], v[5]), pkh(v[6], v[7]));
    return r.v;
}

#define MFMA __builtin_amdgcn_mfma_f32_16x16x32_f16

// Round-17 = round-16 skeleton (45us plateau) + ONE change: tanh via clamped
// Pade[7/6] rational (1 rcp) instead of exp2+rcp (2 serial trans). Removes
// ~512 busy-cyc/tile of quarter-rate trans AND one trans latency from every
// serial tanh chain (the 33% idle at 2.4 waves/SIMD is chain stall).
// kappa(q,kc,j)=q*16+kc*8+j shared by A and B cancels in the contraction.
// C/D: col=lane&15=p, row=(lane>>4)*4+reg -> h=m*16+q*4+r; epilogue lane-local.
__global__ __launch_bounds__(BLK, 2) void curl_mfma(
    const float* __restrict__ x,  const float* __restrict__ W1,
    const float* __restrict__ b1, const float* __restrict__ W2,
    const float* __restrict__ b2, const float* __restrict__ W3,
    float* __restrict__ out, int npts, int iters, int ntiles)
{
    // sA[(m*2+kc)*64 + lane]: packed f16 A fragment. Per-lane 16B -> conflict-free.
    __shared__ uint4  sA[8 * 64];     // 8 KiB
    // Pair tables, slot-permuted so the 4 simultaneous q-addresses are 16B apart.
    __shared__ float4 sW1xy[32], sW1zb[32];   // 1 KiB
    __shared__ float4 sLUTa[32], sLUTb[32];   // 1 KiB

    const int tid  = threadIdx.x;
    const int wv   = tid >> 6;
    const int lane = tid & 63;
    const int p    = lane & 15;   // point-in-tile == B col == D col
    const int q    = lane >> 4;   // k-group (kappa) and h-subgroup of D

    if (tid < 32) {
        // W1 pair tables: tid = qq*8 + kc*4 + u
        {
            const int qq = tid >> 3, kc = (tid >> 2) & 1, u = tid & 3;
            const int k0 = qq * 16 + kc * 8 + u * 2, k1 = k0 + 1;
            const int slot = ((kc * 4 + u) << 2) | qq;
            sW1xy[slot] = make_float4(W1[k0*3+0], W1[k1*3+0], W1[k0*3+1], W1[k1*3+1]);
            sW1zb[slot] = make_float4(W1[k0*3+2], W1[k1*3+2], b1[k0],     b1[k1]);
        }
        // LUT pair tables: tid = m*8 + qq*2 + rp
        {
            const int m = tid >> 3, qq = (tid >> 1) & 3, rp = tid & 1;
            const int h0 = m * 16 + qq * 4 + rp * 2, h1 = h0 + 1;
            sLUTa[tid] = make_float4(b2[h0], b2[h1], W3[h0], W3[h1]);
            sLUTb[tid] = make_float4(W3[64+h0], W3[64+h1], W3[128+h0], W3[128+h1]);
        }
    }

    // Wave wv builds the A fragments for m = wv (W2 row m*16+p, k = kappa(q,kc,j)).
    {
        const int m = wv;
#pragma unroll
        for (int kc = 0; kc < 2; ++kc) {
            const float* src = W2 + (m * 16 + p) * 64 + q * 16 + kc * 8;
            const float4 va = ((const float4*)src)[0];
            const float4 vb = ((const float4*)src)[1];
            const float vv[8] = {va.x, va.y, va.z, va.w, vb.x, vb.y, vb.z, vb.w};
            F16U uh; uh.v = pack8h(vv);
            sA[(m * 2 + kc) * 64 + lane] = uh.u;
        }
    }
    __syncthreads();   // tables ready; no barriers after this point

    // Loop-invariant packed constants.
    const f32x2 one2  = {1.0f, 1.0f};
    const f32x2 none2 = {-1.0f, -1.0f};

    const int gw = blockIdx.x * NWAVE + wv;
    const int nw = gridDim.x * NWAVE;

    for (int it = 0; it < iters; ++it) {
        const int tile = gw + it * nw;
        if (tile >= ntiles) break;         // no barriers -> divergent exit is safe
        const int id = tile * NPT + p;

        float x0 = 0.f, x1 = 0.f, x2 = 0.f;
        if (id < npts) {
            x0 = x[id * 3 + 0];
            x1 = x[id * 3 + 1];
            x2 = x[id * 3 + 2];
        }
        const f32x2 x0_2 = {x0, x0}, x1_2 = {x1, x1}, x2_2 = {x2, x2};

        // ---- Layer 1 + g = D1*W1col, pair-packed; pack into f16 B fragments ----
        f16x8 Bf[4][2];                    // [type][kc] — 32 VGPRs
#pragma unroll
        for (int kc = 0; kc < 2; ++kc) {
            unsigned int wh[4], w0[4], w1[4], w2[4];
#pragma unroll
            for (int u = 0; u < 4; ++u) {
                PairU wxy, wzb;
                wxy.f4 = sW1xy[((kc * 4 + u) << 2) | q];
                wzb.f4 = sW1zb[((kc * 4 + u) << 2) | q];
                f32x2 a = pk_fma(wxy.p[0], x0_2, wzb.p[1]);   // W1x*x0 + b1
                a = pk_fma(wxy.p[1], x1_2, a);
                a = pk_fma(wzb.p[0], x2_2, a);
                const f32x2 th = tanh2r(a);
                const f32x2 t2 = pk_mul(th, th);
                const f32x2 d1 = pk_fma(t2, none2, one2);     // 1 - th^2
                const f32x2 g0 = pk_mul(d1, wxy.p[0]);
                const f32x2 g1 = pk_mul(d1, wxy.p[1]);
                const f32x2 g2 = pk_mul(d1, wzb.p[0]);
                wh[u] = pkh(th.x, th.y);
                w0[u] = pkh(g0.x, g0.y);
                w1[u] = pkh(g1.x, g1.y);
                w2[u] = pkh(g2.x, g2.y);
            }
            F16U t;
            t.u = make_uint4(wh[0], wh[1], wh[2], wh[3]); Bf[0][kc] = t.v;
            t.u = make_uint4(w0[0], w0[1], w0[2], w0[3]); Bf[1][kc] = t.v;
            t.u = make_uint4(w1[0], w1[1], w1[2], w1[3]); Bf[2][kc] = t.v;
            t.u = make_uint4(w2[0], w2[1], w2[2], w2[3]); Bf[3][kc] = t.v;
        }

        // ---- MFMA + pair-packed epilogue; curl via +/- accumulators ----
        f32x2 cp0 = {0.f,0.f}, cp1 = cp0, cp2 = cp0;
        f32x2 cn0 = cp0, cn1 = cp0, cn2 = cp0;
#pragma unroll
        for (int m = 0; m < 4; ++m) {
            F16U A0, A1;
            const uint4* pA = &sA[(m * 2) * 64 + lane];
            A0.u = pA[0];
            A1.u = pA[64];

            AccU a0, a1, a2, a3;
            a0.v = (f32x4){0.f,0.f,0.f,0.f}; a1.v = a0.v; a2.v = a0.v; a3.v = a0.v;
            a0.v = MFMA(A0.v, Bf[0][0], a0.v, 0, 0, 0);
            a1.v = MFMA(A0.v, Bf[1][0], a1.v, 0, 0, 0);
            a2.v = MFMA(A0.v, Bf[2][0], a2.v, 0, 0, 0);
            a3.v = MFMA(A0.v, Bf[3][0], a3.v, 0, 0, 0);
            a0.v = MFMA(A1.v, Bf[0][1], a0.v, 0, 0, 0);
            a1.v = MFMA(A1.v, Bf[1][1], a1.v, 0, 0, 0);
            a2.v = MFMA(A1.v, Bf[2][1], a2.v, 0, 0, 0);
            a3.v = MFMA(A1.v, Bf[3][1], a3.v, 0, 0, 0);

            // Epilogue pairs rp: h = m*16 + q*4 + {2rp, 2rp+1}
#pragma unroll
            for (int rp = 0; rp < 2; ++rp) {
                PairU la, lb;
                la.f4 = sLUTa[m * 8 + q * 2 + rp];
                lb.f4 = sLUTb[m * 8 + q * 2 + rp];
                const f32x2 s0 = pk_add(a0.p[rp], la.p[0]);
                const f32x2 th = tanh2r(s0);
                const f32x2 t2 = pk_mul(th, th);
                const f32x2 d2 = pk_fma(t2, none2, one2);
                const f32x2 e0 = pk_mul(la.p[1], d2);
                const f32x2 e1 = pk_mul(lb.p[0], d2);
                const f32x2 e2 = pk_mul(lb.p[1], d2);
                // c0 += e2*u1 - e1*u2 ; c1 += e0*u2 - e2*u0 ; c2 += e1*u0 - e0*u1
                cp0 = pk_fma(e2, a2.p[rp], cp0);  cn0 = pk_fma(e1, a3.p[rp], cn0);
                cp1 = pk_fma(e0, a3.p[rp], cp1);  cn1 = pk_fma(e2, a1.p[rp], cn1);
                cp2 = pk_fma(e1, a1.p[rp], cp2);  cn2 = pk_fma(e0, a2.p[rp], cn2);
            }
        }

        float c0 = (cp0.x - cn0.x) + (cp0.y - cn0.y);
        float c1 = (cp1.x - cn1.x) + (cp1.y - cn1.y);
        float c2 = (cp2.x - cn2.x) + (cp2.y - cn2.y);

        // Reduce partial curls over the 4 h-subgroups (q dimension).
        c0 += __shfl_xor(c0, 16); c0 += __shfl_xor(c0, 32);
        c1 += __shfl_xor(c1, 16); c1 += __shfl_xor(c1, 32);
        c2 += __shfl_xor(c2, 16); c2 += __shfl_xor(c2, 32);

        // Coalesced store: lane (p,q<3) writes component q of point p.
        if (q < 3 && id < npts) {
            const float cv = (q == 0) ? c0 : ((q == 1) ? c1 : c2);
            out[tile * (NPT * 3) + p * 3 + q] = cv;
        }
    }
}

extern "C" void kernel_launch(void* const* d_in, const int* in_sizes, int n_in,
                              void* d_out, int out_size, void* d_ws, size_t ws_size,
                              hipStream_t stream) {
    const float* x  = (const float*)d_in[0];
    const float* W1 = (const float*)d_in[1];
    const float* b1 = (const float*)d_in[2];
    const float* W2 = (const float*)d_in[3];
    const float* b2 = (const float*)d_in[4];
    const float* W3 = (const float*)d_in[5];
    // d_in[6] (b3) unused: it cancels in the Jacobian.
    float* out = (float*)d_out;

    const int npts   = in_sizes[0] / 3;
    const int ntiles = (npts + NPT - 1) / NPT;
    int blocks = (ntiles + NWAVE - 1) / NWAVE;
    if (blocks > MAXB) blocks = MAXB;
    const int nw    = blocks * NWAVE;
    const int iters = (ntiles + nw - 1) / nw;

    hipLaunchKernelGGL(curl_mfma, dim3(blocks), dim3(BLK), 0, stream,
                       x, W1, b1, W2, b2, W3, out, npts, iters, ntiles);
}

// Round 19
// 104.786 us; speedup vs baseline: 1.0245x; 1.0245x over previous
//
#include <hip/hip_runtime.h>

typedef __attribute__((ext_vector_type(8))) _Float16 f16x8;  // 8 f16 in 4 VGPRs
typedef __attribute__((ext_vector_type(2))) __fp16 fp16x2r;  // cvt_pkrtz return type
typedef __attribute__((ext_vector_type(4))) float f32x4;
typedef __attribute__((ext_vector_type(2))) float f32x2;

#define BLK   256
#define NWAVE 4
#define NPT   16      // points per wave-tile
#define MAXB  2048

union F16U  { uint4 u; f16x8 v; };
union PairU { float4 f4; f32x2 p[2]; };   // view float4 as two aligned f32 pairs
union AccU  { f32x4 v; f32x2 p[2]; };     // view MFMA acc as two aligned pairs

// ---- packed dual-FP32 via native vector ops (compiler selects v_pk_*). ----
__device__ __forceinline__ f32x2 pk_fma(f32x2 a, f32x2 b, f32x2 c) {
    return __builtin_elementwise_fma(a, b, c);
}
__device__ __forceinline__ f32x2 pk_mul(f32x2 a, f32x2 b) { return a * b; }
__device__ __forceinline__ f32x2 pk_add(f32x2 a, f32x2 b) { return a + b; }

// Packed tanh pair via exp2+rcp (r17's Pade rational REGRESSED: trans ops are
// cheap to issue; instruction COUNT is the binding resource).
__device__ __forceinline__ f32x2 tanh2(f32x2 a, f32x2 cst2, f32x2 one2, f32x2 ntwo2) {
    f32x2 earg = pk_mul(a, cst2);
    f32x2 e;
    e.x = __builtin_amdgcn_exp2f(earg.x);
    e.y = __builtin_amdgcn_exp2f(earg.y);
    f32x2 ep1 = pk_add(e, one2);
    f32x2 r;
    r.x = __builtin_amdgcn_rcpf(ep1.x);
    r.y = __builtin_amdgcn_rcpf(ep1.y);
    return pk_fma(ntwo2, r, one2);     // 1 - 2/(e^2a+1)
}

// Two f32 -> packed f16x2 in one v_cvt_pkrtz_f16_f32.
__device__ __forceinline__ unsigned int pkh(float a, float b) {
    union { fp16x2r h; unsigned int u; } t;
    t.h = __builtin_amdgcn_cvt_pkrtz(a, b);
    return t.u;
}

__device__ __forceinline__ f16x8 pack8h(const float* v) {
    F16U r;
    r.u = make_uint4(pkh(v[0], v[1]), pkh(v[2], v[3]),
                     pkh(v[4], v[5]), pkh(v[6], v[7]));
    return r.v;
}

#define MFMA __builtin_amdgcn_mfma_f32_16x16x32_f16

// Round-19 = round-18 resubmitted (GPU acquisition timeout; never ran).
// = round-16 (best, 44.8us) + ONE change: software-pipelined x-loads.
// Each tile previously began with 3 dependent global loads (~200-400 cyc L2
// latency) exposed at 2.4 waves/SIMD on every one of 32 tiles/SIMD. Now tile
// t+1's loads issue at the top of tile t's body and the ~1400-cyc tile compute
// hides them. Cost: 3 VGPRs. (r17's Pade tanh reverted — it regressed;
// instruction count, not trans throughput, is the binding resource.)
// kappa(q,kc,j)=q*16+kc*8+j shared by A and B cancels in the contraction.
// C/D: col=lane&15=p, row=(lane>>4)*4+reg -> h=m*16+q*4+r; epilogue lane-local.
__global__ __launch_bounds__(BLK, 2) void curl_mfma(
    const float* __restrict__ x,  const float* __restrict__ W1,
    const float* __restrict__ b1, const float* __restrict__ W2,
    const float* __restrict__ b2, const float* __restrict__ W3,
    float* __restrict__ out, int npts, int iters, int ntiles)
{
    // sA[(m*2+kc)*64 + lane]: packed f16 A fragment. Per-lane 16B -> conflict-free.
    __shared__ uint4  sA[8 * 64];     // 8 KiB
    // Pair tables, slot-permuted so the 4 simultaneous q-addresses are 16B apart.
    __shared__ float4 sW1xy[32], sW1zb[32];   // 1 KiB
    __shared__ float4 sLUTa[32], sLUTb[32];   // 1 KiB

    const int tid  = threadIdx.x;
    const int wv   = tid >> 6;
    const int lane = tid & 63;
    const int p    = lane & 15;   // point-in-tile == B col == D col
    const int q    = lane >> 4;   // k-group (kappa) and h-subgroup of D

    if (tid < 32) {
        // W1 pair tables: tid = qq*8 + kc*4 + u
        {
            const int qq = tid >> 3, kc = (tid >> 2) & 1, u = tid & 3;
            const int k0 = qq * 16 + kc * 8 + u * 2, k1 = k0 + 1;
            const int slot = ((kc * 4 + u) << 2) | qq;
            sW1xy[slot] = make_float4(W1[k0*3+0], W1[k1*3+0], W1[k0*3+1], W1[k1*3+1]);
            sW1zb[slot] = make_float4(W1[k0*3+2], W1[k1*3+2], b1[k0],     b1[k1]);
        }
        // LUT pair tables: tid = m*8 + qq*2 + rp
        {
            const int m = tid >> 3, qq = (tid >> 1) & 3, rp = tid & 1;
            const int h0 = m * 16 + qq * 4 + rp * 2, h1 = h0 + 1;
            sLUTa[tid] = make_float4(b2[h0], b2[h1], W3[h0], W3[h1]);
            sLUTb[tid] = make_float4(W3[64+h0], W3[64+h1], W3[128+h0], W3[128+h1]);
        }
    }

    // Wave wv builds the A fragments for m = wv (W2 row m*16+p, k = kappa(q,kc,j)).
    {
        const int m = wv;
#pragma unroll
        for (int kc = 0; kc < 2; ++kc) {
            const float* src = W2 + (m * 16 + p) * 64 + q * 16 + kc * 8;
            const float4 va = ((const float4*)src)[0];
            const float4 vb = ((const float4*)src)[1];
            const float vv[8] = {va.x, va.y, va.z, va.w, vb.x, vb.y, vb.z, vb.w};
            F16U uh; uh.v = pack8h(vv);
            sA[(m * 2 + kc) * 64 + lane] = uh.u;
        }
    }
    __syncthreads();   // tables ready; no barriers after this point

    // Loop-invariant packed constants.
    const f32x2 one2  = {1.0f, 1.0f};
    const f32x2 none2 = {-1.0f, -1.0f};
    const f32x2 ntwo2 = {-2.0f, -2.0f};
    const f32x2 cst2  = {2.8853900817779268f, 2.8853900817779268f};

    const int gw = blockIdx.x * NWAVE + wv;
    const int nw = gridDim.x * NWAVE;

    // ---- Prologue: load x for the first tile ----
    float x0 = 0.f, x1 = 0.f, x2 = 0.f;
    if (gw < ntiles) {
        const int id0 = gw * NPT + p;
        if (id0 < npts) {
            x0 = x[id0 * 3 + 0];
            x1 = x[id0 * 3 + 1];
            x2 = x[id0 * 3 + 2];
        }
    }

    for (int it = 0; it < iters; ++it) {
        const int tile = gw + it * nw;
        if (tile >= ntiles) break;         // no barriers -> divergent exit is safe
        const int id = tile * NPT + p;

        // ---- Issue NEXT tile's x-loads now; tile compute hides the latency ----
        float xn0 = 0.f, xn1 = 0.f, xn2 = 0.f;
        {
            const int tnx = tile + nw;
            if (tnx < ntiles) {
                const int idn = tnx * NPT + p;
                if (idn < npts) {
                    xn0 = x[idn * 3 + 0];
                    xn1 = x[idn * 3 + 1];
                    xn2 = x[idn * 3 + 2];
                }
            }
        }

        const f32x2 x0_2 = {x0, x0}, x1_2 = {x1, x1}, x2_2 = {x2, x2};

        // ---- Layer 1 + g = D1*W1col, pair-packed; pack into f16 B fragments ----
        f16x8 Bf[4][2];                    // [type][kc] — 32 VGPRs
#pragma unroll
        for (int kc = 0; kc < 2; ++kc) {
            unsigned int wh[4], w0[4], w1[4], w2[4];
#pragma unroll
            for (int u = 0; u < 4; ++u) {
                PairU wxy, wzb;
                wxy.f4 = sW1xy[((kc * 4 + u) << 2) | q];
                wzb.f4 = sW1zb[((kc * 4 + u) << 2) | q];
                f32x2 a = pk_fma(wxy.p[0], x0_2, wzb.p[1]);   // W1x*x0 + b1
                a = pk_fma(wxy.p[1], x1_2, a);
                a = pk_fma(wzb.p[0], x2_2, a);
                const f32x2 th = tanh2(a, cst2, one2, ntwo2);
                const f32x2 t2 = pk_mul(th, th);
                const f32x2 d1 = pk_fma(t2, none2, one2);     // 1 - th^2
                const f32x2 g0 = pk_mul(d1, wxy.p[0]);
                const f32x2 g1 = pk_mul(d1, wxy.p[1]);
                const f32x2 g2 = pk_mul(d1, wzb.p[0]);
                wh[u] = pkh(th.x, th.y);
                w0[u] = pkh(g0.x, g0.y);
                w1[u] = pkh(g1.x, g1.y);
                w2[u] = pkh(g2.x, g2.y);
            }
            F16U t;
            t.u = make_uint4(wh[0], wh[1], wh[2], wh[3]); Bf[0][kc] = t.v;
            t.u = make_uint4(w0[0], w0[1], w0[2], w0[3]); Bf[1][kc] = t.v;
            t.u = make_uint4(w1[0], w1[1], w1[2], w1[3]); Bf[2][kc] = t.v;
            t.u = make_uint4(w2[0], w2[1], w2[2], w2[3]); Bf[3][kc] = t.v;
        }

        // ---- MFMA + pair-packed epilogue; curl via +/- accumulators ----
        f32x2 cp0 = {0.f,0.f}, cp1 = cp0, cp2 = cp0;
        f32x2 cn0 = cp0, cn1 = cp0, cn2 = cp0;
#pragma unroll
        for (int m = 0; m < 4; ++m) {
            F16U A0, A1;
            const uint4* pA = &sA[(m * 2) * 64 + lane];
            A0.u = pA[0];
            A1.u = pA[64];

            AccU a0, a1, a2, a3;
            a0.v = (f32x4){0.f,0.f,0.f,0.f}; a1.v = a0.v; a2.v = a0.v; a3.v = a0.v;
            a0.v = MFMA(A0.v, Bf[0][0], a0.v, 0, 0, 0);
            a1.v = MFMA(A0.v, Bf[1][0], a1.v, 0, 0, 0);
            a2.v = MFMA(A0.v, Bf[2][0], a2.v, 0, 0, 0);
            a3.v = MFMA(A0.v, Bf[3][0], a3.v, 0, 0, 0);
            a0.v = MFMA(A1.v, Bf[0][1], a0.v, 0, 0, 0);
            a1.v = MFMA(A1.v, Bf[1][1], a1.v, 0, 0, 0);
            a2.v = MFMA(A1.v, Bf[2][1], a2.v, 0, 0, 0);
            a3.v = MFMA(A1.v, Bf[3][1], a3.v, 0, 0, 0);

            // Epilogue pairs rp: h = m*16 + q*4 + {2rp, 2rp+1}
#pragma unroll
            for (int rp = 0; rp < 2; ++rp) {
                PairU la, lb;
                la.f4 = sLUTa[m * 8 + q * 2 + rp];
                lb.f4 = sLUTb[m * 8 + q * 2 + rp];
                const f32x2 s0 = pk_add(a0.p[rp], la.p[0]);
                const f32x2 th = tanh2(s0, cst2, one2, ntwo2);
                const f32x2 t2 = pk_mul(th, th);
                const f32x2 d2 = pk_fma(t2, none2, one2);
                const f32x2 e0 = pk_mul(la.p[1], d2);
                const f32x2 e1 = pk_mul(lb.p[0], d2);
                const f32x2 e2 = pk_mul(lb.p[1], d2);
                // c0 += e2*u1 - e1*u2 ; c1 += e0*u2 - e2*u0 ; c2 += e1*u0 - e0*u1
                cp0 = pk_fma(e2, a2.p[rp], cp0);  cn0 = pk_fma(e1, a3.p[rp], cn0);
                cp1 = pk_fma(e0, a3.p[rp], cp1);  cn1 = pk_fma(e2, a1.p[rp], cn1);
                cp2 = pk_fma(e1, a1.p[rp], cp2);  cn2 = pk_fma(e0, a2.p[rp], cn2);
            }
        }

        float c0 = (cp0.x - cn0.x) + (cp0.y - cn0.y);
        float c1 = (cp1.x - cn1.x) + (cp1.y - cn1.y);
        float c2 = (cp2.x - cn2.x) + (cp2.y - cn2.y);

        // Reduce partial curls over the 4 h-subgroups (q dimension).
        c0 += __shfl_xor(c0, 16); c0 += __shfl_xor(c0, 32);
        c1 += __shfl_xor(c1, 16); c1 += __shfl_xor(c1, 32);
        c2 += __shfl_xor(c2, 16); c2 += __shfl_xor(c2, 32);

        // Coalesced store: lane (p,q<3) writes component q of point p.
        if (q < 3 && id < npts) {
            const float cv = (q == 0) ? c0 : ((q == 1) ? c1 : c2);
            out[tile * (NPT * 3) + p * 3 + q] = cv;
        }

        // Rotate in the prefetched x.
        x0 = xn0; x1 = xn1; x2 = xn2;
    }
}

extern "C" void kernel_launch(void* const* d_in, const int* in_sizes, int n_in,
                              void* d_out, int out_size, void* d_ws, size_t ws_size,
                              hipStream_t stream) {
    const float* x  = (const float*)d_in[0];
    const float* W1 = (const float*)d_in[1];
    const float* b1 = (const float*)d_in[2];
    const float* W2 = (const float*)d_in[3];
    const float* b2 = (const float*)d_in[4];
    const float* W3 = (const float*)d_in[5];
    // d_in[6] (b3) unused: it cancels in the Jacobian.
    float* out = (float*)d_out;

    const int npts   = in_sizes[0] / 3;
    const int ntiles = (npts + NPT - 1) / NPT;
    int blocks = (ntiles + NWAVE - 1) / NWAVE;
    if (blocks > MAXB) blocks = MAXB;
    const int nw    = blocks * NWAVE;
    const int iters = (ntiles + nw - 1) / nw;

    hipLaunchKernelGGL(curl_mfma, dim3(blocks), dim3(BLK), 0, stream,
                       x, W1, b1, W2, b2, W3, out, npts, iters, ntiles);
}

// Round 20
// 104.741 us; speedup vs baseline: 1.0250x; 1.0004x over previous
//
#include <hip/hip_runtime.h>

typedef __attribute__((ext_vector_type(8))) _Float16 f16x8;  // 8 f16 in 4 VGPRs
typedef __attribute__((ext_vector_type(2))) __fp16 fp16x2r;  // cvt_pkrtz return type
typedef __attribute__((ext_vector_type(4))) float f32x4;
typedef __attribute__((ext_vector_type(2))) float f32x2;

#define BLK   256
#define NWAVE 4
#define NPT   16      // points per wave-tile
#define MAXB  2048

union F16U  { uint4 u; f16x8 v; };
union PairU { float4 f4; f32x2 p[2]; };   // view float4 as two aligned f32 pairs
union AccU  { f32x4 v; f32x2 p[2]; };     // view MFMA acc as two aligned pairs

// ---- packed dual-FP32 via native vector ops (compiler selects v_pk_*). ----
__device__ __forceinline__ f32x2 pk_fma(f32x2 a, f32x2 b, f32x2 c) {
    return __builtin_elementwise_fma(a, b, c);
}
__device__ __forceinline__ f32x2 pk_mul(f32x2 a, f32x2 b) { return a * b; }
__device__ __forceinline__ f32x2 pk_add(f32x2 a, f32x2 b) { return a + b; }

// Packed tanh pair via exp2+rcp (Pade regressed in r17: issue count rules).
__device__ __forceinline__ f32x2 tanh2(f32x2 a) {
    const f32x2 one2  = {1.0f, 1.0f};
    const f32x2 ntwo2 = {-2.0f, -2.0f};
    const f32x2 cst2  = {2.8853900817779268f, 2.8853900817779268f};
    f32x2 earg = pk_mul(a, cst2);
    f32x2 e;
    e.x = __builtin_amdgcn_exp2f(earg.x);
    e.y = __builtin_amdgcn_exp2f(earg.y);
    f32x2 ep1 = pk_add(e, one2);
    f32x2 r;
    r.x = __builtin_amdgcn_rcpf(ep1.x);
    r.y = __builtin_amdgcn_rcpf(ep1.y);
    return pk_fma(ntwo2, r, one2);     // 1 - 2/(e^2a+1)
}

// Two f32 -> packed f16x2 in one v_cvt_pkrtz_f16_f32.
__device__ __forceinline__ unsigned int pkh(float a, float b) {
    union { fp16x2r h; unsigned int u; } t;
    t.h = __builtin_amdgcn_cvt_pkrtz(a, b);
    return t.u;
}

__device__ __forceinline__ f16x8 pack8h(const float* v) {
    F16U r;
    r.u = make_uint4(pkh(v[0], v[1]), pkh(v[2], v[3]),
                     pkh(v[4], v[5]), pkh(v[6], v[7]));
    return r.v;
}

#define MFMA __builtin_amdgcn_mfma_f32_16x16x32_f16

// Layer 1 + g = D1*W1col, pair-packed; packs into f16 B fragments.
__device__ __forceinline__ void computeB(
    float x0, float x1, float x2,
    const float4* sW1xy, const float4* sW1zb, int q, f16x8 (&Bf)[4][2])
{
    const f32x2 one2  = {1.0f, 1.0f};
    const f32x2 none2 = {-1.0f, -1.0f};
    const f32x2 x0_2 = {x0, x0}, x1_2 = {x1, x1}, x2_2 = {x2, x2};
#pragma unroll
    for (int kc = 0; kc < 2; ++kc) {
        unsigned int wh[4], w0[4], w1[4], w2[4];
#pragma unroll
        for (int u = 0; u < 4; ++u) {
            PairU wxy, wzb;
            wxy.f4 = sW1xy[((kc * 4 + u) << 2) | q];
            wzb.f4 = sW1zb[((kc * 4 + u) << 2) | q];
            f32x2 a = pk_fma(wxy.p[0], x0_2, wzb.p[1]);   // W1x*x0 + b1
            a = pk_fma(wxy.p[1], x1_2, a);
            a = pk_fma(wzb.p[0], x2_2, a);
            const f32x2 th = tanh2(a);
            const f32x2 t2 = pk_mul(th, th);
            const f32x2 d1 = pk_fma(t2, none2, one2);     // 1 - th^2
            const f32x2 g0 = pk_mul(d1, wxy.p[0]);
            const f32x2 g1 = pk_mul(d1, wxy.p[1]);
            const f32x2 g2 = pk_mul(d1, wzb.p[0]);
            wh[u] = pkh(th.x, th.y);
            w0[u] = pkh(g0.x, g0.y);
            w1[u] = pkh(g1.x, g1.y);
            w2[u] = pkh(g2.x, g2.y);
        }
        F16U t;
        t.u = make_uint4(wh[0], wh[1], wh[2], wh[3]); Bf[0][kc] = t.v;
        t.u = make_uint4(w0[0], w0[1], w0[2], w0[3]); Bf[1][kc] = t.v;
        t.u = make_uint4(w1[0], w1[1], w1[2], w1[3]); Bf[2][kc] = t.v;
        t.u = make_uint4(w2[0], w2[1], w2[2], w2[3]); Bf[3][kc] = t.v;
    }
}

// MFMA + pair-packed epilogue + store for one tile. m-loop unroll-1: acc = 16 regs.
__device__ __forceinline__ void processTile(
    const f16x8 (&Bf)[4][2], const uint4* sA,
    const float4* sLUTa, const float4* sLUTb,
    int lane, int q, int p, int tile, int npts, float* __restrict__ out)
{
    const f32x2 one2  = {1.0f, 1.0f};
    const f32x2 none2 = {-1.0f, -1.0f};
    f32x2 cp0 = {0.f,0.f}, cp1 = cp0, cp2 = cp0;
    f32x2 cn0 = cp0, cn1 = cp0, cn2 = cp0;
#pragma unroll 1
    for (int m = 0; m < 4; ++m) {
        F16U A0, A1;
        const uint4* pA = &sA[(m * 2) * 64 + lane];
        A0.u = pA[0];
        A1.u = pA[64];

        AccU a0, a1, a2, a3;
        a0.v = (f32x4){0.f,0.f,0.f,0.f}; a1.v = a0.v; a2.v = a0.v; a3.v = a0.v;
        a0.v = MFMA(A0.v, Bf[0][0], a0.v, 0, 0, 0);
        a1.v = MFMA(A0.v, Bf[1][0], a1.v, 0, 0, 0);
        a2.v = MFMA(A0.v, Bf[2][0], a2.v, 0, 0, 0);
        a3.v = MFMA(A0.v, Bf[3][0], a3.v, 0, 0, 0);
        a0.v = MFMA(A1.v, Bf[0][1], a0.v, 0, 0, 0);
        a1.v = MFMA(A1.v, Bf[1][1], a1.v, 0, 0, 0);
        a2.v = MFMA(A1.v, Bf[2][1], a2.v, 0, 0, 0);
        a3.v = MFMA(A1.v, Bf[3][1], a3.v, 0, 0, 0);

        // Epilogue pairs rp: h = m*16 + q*4 + {2rp, 2rp+1}
#pragma unroll
        for (int rp = 0; rp < 2; ++rp) {
            PairU la, lb;
            la.f4 = sLUTa[m * 8 + q * 2 + rp];
            lb.f4 = sLUTb[m * 8 + q * 2 + rp];
            const f32x2 s0 = pk_add(a0.p[rp], la.p[0]);
            const f32x2 th = tanh2(s0);
            const f32x2 t2 = pk_mul(th, th);
            const f32x2 d2 = pk_fma(t2, none2, one2);
            const f32x2 e0 = pk_mul(la.p[1], d2);
            const f32x2 e1 = pk_mul(lb.p[0], d2);
            const f32x2 e2 = pk_mul(lb.p[1], d2);
            // c0 += e2*u1 - e1*u2 ; c1 += e0*u2 - e2*u0 ; c2 += e1*u0 - e0*u1
            cp0 = pk_fma(e2, a2.p[rp], cp0);  cn0 = pk_fma(e1, a3.p[rp], cn0);
            cp1 = pk_fma(e0, a3.p[rp], cp1);  cn1 = pk_fma(e2, a1.p[rp], cn1);
            cp2 = pk_fma(e1, a1.p[rp], cp2);  cn2 = pk_fma(e0, a2.p[rp], cn2);
        }
    }

    float c0 = (cp0.x - cn0.x) + (cp0.y - cn0.y);
    float c1 = (cp1.x - cn1.x) + (cp1.y - cn1.y);
    float c2 = (cp2.x - cn2.x) + (cp2.y - cn2.y);

    c0 += __shfl_xor(c0, 16); c0 += __shfl_xor(c0, 32);
    c1 += __shfl_xor(c1, 16); c1 += __shfl_xor(c1, 32);
    c2 += __shfl_xor(c2, 16); c2 += __shfl_xor(c2, 32);

    const int id = tile * NPT + p;
    if (q < 3 && id < npts) {
        const float cv = (q == 0) ? c0 : ((q == 1) ? c1 : c2);
        out[tile * (NPT * 3) + p * 3 + q] = cv;
    }
}

// Round-20: 2-deep TILE PIPELINE within each wave. r19 closed the cycle model:
// per-tile slot is ~3.3k cyc vs ~800 issue — latency-bound at 2.5 waves/SIMD
// (unified ~200-reg footprint caps residency; all launch_bounds tried). The
// remaining mechanism is intra-wave overlap: computeB(t+1) (LDS reads + tanh
// chains) is issued BEFORE processTile(t) (MFMA + epilogue) — two independent
// blocks the scheduler interleaves, filling each other's stalls (T14 analog).
// m-loop unroll-1 keeps acc at 16 regs (BfA+BfB = 64). Watch FETCH/WRITE for
// spill; revert if ballooned.
__global__ __launch_bounds__(BLK, 2) void curl_mfma(
    const float* __restrict__ x,  const float* __restrict__ W1,
    const float* __restrict__ b1, const float* __restrict__ W2,
    const float* __restrict__ b2, const float* __restrict__ W3,
    float* __restrict__ out, int npts, int iters, int ntiles)
{
    __shared__ uint4  sA[8 * 64];     // 8 KiB packed f16 A fragments
    __shared__ float4 sW1xy[32], sW1zb[32];   // 1 KiB
    __shared__ float4 sLUTa[32], sLUTb[32];   // 1 KiB

    const int tid  = threadIdx.x;
    const int wv   = tid >> 6;
    const int lane = tid & 63;
    const int p    = lane & 15;   // point-in-tile == B col == D col
    const int q    = lane >> 4;   // k-group (kappa) and h-subgroup of D

    if (tid < 32) {
        {
            const int qq = tid >> 3, kc = (tid >> 2) & 1, u = tid & 3;
            const int k0 = qq * 16 + kc * 8 + u * 2, k1 = k0 + 1;
            const int slot = ((kc * 4 + u) << 2) | qq;
            sW1xy[slot] = make_float4(W1[k0*3+0], W1[k1*3+0], W1[k0*3+1], W1[k1*3+1]);
            sW1zb[slot] = make_float4(W1[k0*3+2], W1[k1*3+2], b1[k0],     b1[k1]);
        }
        {
            const int m = tid >> 3, qq = (tid >> 1) & 3, rp = tid & 1;
            const int h0 = m * 16 + qq * 4 + rp * 2, h1 = h0 + 1;
            sLUTa[tid] = make_float4(b2[h0], b2[h1], W3[h0], W3[h1]);
            sLUTb[tid] = make_float4(W3[64+h0], W3[64+h1], W3[128+h0], W3[128+h1]);
        }
    }

    // Wave wv builds the A fragments for m = wv (W2 row m*16+p, k = kappa(q,kc,j)).
    {
        const int m = wv;
#pragma unroll
        for (int kc = 0; kc < 2; ++kc) {
            const float* src = W2 + (m * 16 + p) * 64 + q * 16 + kc * 8;
            const float4 va = ((const float4*)src)[0];
            const float4 vb = ((const float4*)src)[1];
            const float vv[8] = {va.x, va.y, va.z, va.w, vb.x, vb.y, vb.z, vb.w};
            F16U uh; uh.v = pack8h(vv);
            sA[(m * 2 + kc) * 64 + lane] = uh.u;
        }
    }
    __syncthreads();   // tables ready; no barriers after this point

    const int gw = blockIdx.x * NWAVE + wv;
    const int nw = gridDim.x * NWAVE;

    // x loader: zero-fills out-of-range (computeB on zeros is harmless dead work).
    auto loadx = [&](int t, float& a, float& b, float& c) {
        a = 0.f; b = 0.f; c = 0.f;
        if (t < ntiles) {
            const int idn = t * NPT + p;
            if (idn < npts) {
                a = x[idn * 3 + 0];
                b = x[idn * 3 + 1];
                c = x[idn * 3 + 2];
            }
        }
    };

    float xb0, xb1, xb2, xc0, xc1, xc2;
    f16x8 BfA[4][2], BfB[4][2];

    // Prologue: BfA = B(tile 0); xb = x(tile 1).
    {
        float xa0, xa1, xa2;
        loadx(gw, xa0, xa1, xa2);
        loadx(gw + nw, xb0, xb1, xb2);
        computeB(xa0, xa1, xa2, sW1xy, sW1zb, q, BfA);
    }

    for (int it = 0; it < iters; it += 2) {
        const int tA = gw + it * nw;
        if (tA >= ntiles) break;
        const int tB = tA + nw;

        loadx(tA + 2 * nw, xc0, xc1, xc2);              // x(t+2)
        computeB(xb0, xb1, xb2, sW1xy, sW1zb, q, BfB);  // B(t+1) — overlaps ↓
        processTile(BfA, sA, sLUTa, sLUTb, lane, q, p, tA, npts, out);

        loadx(tA + 3 * nw, xb0, xb1, xb2);              // x(t+3)
        if (tB >= ntiles) break;
        computeB(xc0, xc1, xc2, sW1xy, sW1zb, q, BfA);  // B(t+2) — overlaps ↓
        processTile(BfB, sA, sLUTa, sLUTb, lane, q, p, tB, npts, out);
    }
}

extern "C" void kernel_launch(void* const* d_in, const int* in_sizes, int n_in,
                              void* d_out, int out_size, void* d_ws, size_t ws_size,
                              hipStream_t stream) {
    const float* x  = (const float*)d_in[0];
    const float* W1 = (const float*)d_in[1];
    const float* b1 = (const float*)d_in[2];
    const float* W2 = (const float*)d_in[3];
    const float* b2 = (const float*)d_in[4];
    const float* W3 = (const float*)d_in[5];
    // d_in[6] (b3) unused: it cancels in the Jacobian.
    float* out = (float*)d_out;

    const int npts   = in_sizes[0] / 3;
    const int ntiles = (npts + NPT - 1) / NPT;
    int blocks = (ntiles + NWAVE - 1) / NWAVE;
    if (blocks > MAXB) blocks = MAXB;
    const int nw    = blocks * NWAVE;
    const int iters = (ntiles + nw - 1) / nw;

    hipLaunchKernelGGL(curl_mfma, dim3(blocks), dim3(BLK), 0, stream,
                       x, W1, b1, W2, b2, W3, out, npts, iters, ntiles);
}

// Round 21
// 103.502 us; speedup vs baseline: 1.0372x; 1.0120x over previous
//
#include <hip/hip_runtime.h>

typedef __attribute__((ext_vector_type(8))) _Float16 f16x8;  // 8 f16 in 4 VGPRs
typedef __attribute__((ext_vector_type(2))) __fp16 fp16x2r;  // cvt_pkrtz return type
typedef __attribute__((ext_vector_type(4))) float f32x4;
typedef __attribute__((ext_vector_type(2))) float f32x2;

#define BLK   256
#define NWAVE 4
#define NPT   16      // points per wave-tile
#define MAXB  2048

union F16U  { uint4 u; f16x8 v; };
union PairU { float4 f4; f32x2 p[2]; };   // view float4 as two aligned f32 pairs
union AccU  { f32x4 v; f32x2 p[2]; };     // view MFMA acc as two aligned pairs

// ---- packed dual-FP32 via native vector ops (compiler selects v_pk_*). ----
__device__ __forceinline__ f32x2 pk_fma(f32x2 a, f32x2 b, f32x2 c) {
    return __builtin_elementwise_fma(a, b, c);
}
__device__ __forceinline__ f32x2 pk_mul(f32x2 a, f32x2 b) { return a * b; }
__device__ __forceinline__ f32x2 pk_add(f32x2 a, f32x2 b) { return a + b; }

// Packed tanh pair via exp2+rcp. (Pade rational regressed in r17 — instruction
// COUNT is the binding resource on this kernel, trans ops issue cheaply.)
__device__ __forceinline__ f32x2 tanh2(f32x2 a, f32x2 cst2, f32x2 one2, f32x2 ntwo2) {
    f32x2 earg = pk_mul(a, cst2);
    f32x2 e;
    e.x = __builtin_amdgcn_exp2f(earg.x);
    e.y = __builtin_amdgcn_exp2f(earg.y);
    f32x2 ep1 = pk_add(e, one2);
    f32x2 r;
    r.x = __builtin_amdgcn_rcpf(ep1.x);
    r.y = __builtin_amdgcn_rcpf(ep1.y);
    return pk_fma(ntwo2, r, one2);     // 1 - 2/(e^2a+1)
}

// Two f32 -> packed f16x2 in one v_cvt_pkrtz_f16_f32.
__device__ __forceinline__ unsigned int pkh(float a, float b) {
    union { fp16x2r h; unsigned int u; } t;
    t.h = __builtin_amdgcn_cvt_pkrtz(a, b);
    return t.u;
}

__device__ __forceinline__ f16x8 pack8h(const float* v) {
    F16U r;
    r.u = make_uint4(pkh(v[0], v[1]), pkh(v[2], v[3]),
                     pkh(v[4], v[5]), pkh(v[6], v[7]));
    return r.v;
}

#define MFMA __builtin_amdgcn_mfma_f32_16x16x32_f16

// FINAL (round-21) = round-16 verbatim — the session best (44.7us dispatch,
// 104.0us scored; 9x vs the 406us starting kernel). Six subsequent
// single-variable probes (launch_bounds 1/4, full m-unroll, Pade tanh,
// x-prefetch, 2-deep tile pipeline) were all null or regressive; r20's
// pipeline cost 28 VGPRs of B-state and 5pts of occupancy for −13%.
// Structural constraint at the wall: unified VGPR+AGPR footprint caps
// residency at ~2.5 waves/SIMD; at that residency ~33% of issue slots are
// dependency/LDS-latency stall, and the compiler's ~3x instruction
// amplification (vs hand count) is not attackable without disasm.
// Design recap: f16 single-term 16x16x32 MFMA (absmax 0.0078 vs thr 0.0256);
// kappa(q,kc,j)=q*16+kc*8+j shared by A and B cancels in the contraction so
// each lane's layer-1 output IS its B fragment (no LDS staging, no barriers);
// pair-packed (v_pk_*) layer-1 + epilogue; curl via +/- accumulators.
// C/D: col=lane&15=p, row=(lane>>4)*4+reg -> h=m*16+q*4+r; epilogue lane-local.
__global__ __launch_bounds__(BLK, 2) void curl_mfma(
    const float* __restrict__ x,  const float* __restrict__ W1,
    const float* __restrict__ b1, const float* __restrict__ W2,
    const float* __restrict__ b2, const float* __restrict__ W3,
    float* __restrict__ out, int npts, int iters, int ntiles)
{
    // sA[(m*2+kc)*64 + lane]: packed f16 A fragment. Per-lane 16B -> conflict-free.
    __shared__ uint4  sA[8 * 64];     // 8 KiB
    // Pair tables, slot-permuted so the 4 simultaneous q-addresses are 16B apart.
    __shared__ float4 sW1xy[32], sW1zb[32];   // 1 KiB
    __shared__ float4 sLUTa[32], sLUTb[32];   // 1 KiB

    const int tid  = threadIdx.x;
    const int wv   = tid >> 6;
    const int lane = tid & 63;
    const int p    = lane & 15;   // point-in-tile == B col == D col
    const int q    = lane >> 4;   // k-group (kappa) and h-subgroup of D

    if (tid < 32) {
        // W1 pair tables: tid = qq*8 + kc*4 + u
        {
            const int qq = tid >> 3, kc = (tid >> 2) & 1, u = tid & 3;
            const int k0 = qq * 16 + kc * 8 + u * 2, k1 = k0 + 1;
            const int slot = ((kc * 4 + u) << 2) | qq;
            sW1xy[slot] = make_float4(W1[k0*3+0], W1[k1*3+0], W1[k0*3+1], W1[k1*3+1]);
            sW1zb[slot] = make_float4(W1[k0*3+2], W1[k1*3+2], b1[k0],     b1[k1]);
        }
        // LUT pair tables: tid = m*8 + qq*2 + rp
        {
            const int m = tid >> 3, qq = (tid >> 1) & 3, rp = tid & 1;
            const int h0 = m * 16 + qq * 4 + rp * 2, h1 = h0 + 1;
            sLUTa[tid] = make_float4(b2[h0], b2[h1], W3[h0], W3[h1]);
            sLUTb[tid] = make_float4(W3[64+h0], W3[64+h1], W3[128+h0], W3[128+h1]);
        }
    }

    // Wave wv builds the A fragments for m = wv (W2 row m*16+p, k = kappa(q,kc,j)).
    {
        const int m = wv;
#pragma unroll
        for (int kc = 0; kc < 2; ++kc) {
            const float* src = W2 + (m * 16 + p) * 64 + q * 16 + kc * 8;
            const float4 va = ((const float4*)src)[0];
            const float4 vb = ((const float4*)src)[1];
            const float vv[8] = {va.x, va.y, va.z, va.w, vb.x, vb.y, vb.z, vb.w};
            F16U uh; uh.v = pack8h(vv);
            sA[(m * 2 + kc) * 64 + lane] = uh.u;
        }
    }
    __syncthreads();   // tables ready; no barriers after this point

    // Loop-invariant packed constants.
    const f32x2 one2  = {1.0f, 1.0f};
    const f32x2 none2 = {-1.0f, -1.0f};
    const f32x2 ntwo2 = {-2.0f, -2.0f};
    const f32x2 cst2  = {2.8853900817779268f, 2.8853900817779268f};

    const int gw = blockIdx.x * NWAVE + wv;
    const int nw = gridDim.x * NWAVE;

    for (int it = 0; it < iters; ++it) {
        const int tile = gw + it * nw;
        if (tile >= ntiles) break;         // no barriers -> divergent exit is safe
        const int id = tile * NPT + p;

        float x0 = 0.f, x1 = 0.f, x2 = 0.f;
        if (id < npts) {
            x0 = x[id * 3 + 0];
            x1 = x[id * 3 + 1];
            x2 = x[id * 3 + 2];
        }
        const f32x2 x0_2 = {x0, x0}, x1_2 = {x1, x1}, x2_2 = {x2, x2};

        // ---- Layer 1 + g = D1*W1col, pair-packed; pack into f16 B fragments ----
        f16x8 Bf[4][2];                    // [type][kc] — 32 VGPRs
#pragma unroll
        for (int kc = 0; kc < 2; ++kc) {
            unsigned int wh[4], w0[4], w1[4], w2[4];
#pragma unroll
            for (int u = 0; u < 4; ++u) {
                PairU wxy, wzb;
                wxy.f4 = sW1xy[((kc * 4 + u) << 2) | q];
                wzb.f4 = sW1zb[((kc * 4 + u) << 2) | q];
                f32x2 a = pk_fma(wxy.p[0], x0_2, wzb.p[1]);   // W1x*x0 + b1
                a = pk_fma(wxy.p[1], x1_2, a);
                a = pk_fma(wzb.p[0], x2_2, a);
                const f32x2 th = tanh2(a, cst2, one2, ntwo2);
                const f32x2 t2 = pk_mul(th, th);
                const f32x2 d1 = pk_fma(t2, none2, one2);     // 1 - th^2
                const f32x2 g0 = pk_mul(d1, wxy.p[0]);
                const f32x2 g1 = pk_mul(d1, wxy.p[1]);
                const f32x2 g2 = pk_mul(d1, wzb.p[0]);
                wh[u] = pkh(th.x, th.y);
                w0[u] = pkh(g0.x, g0.y);
                w1[u] = pkh(g1.x, g1.y);
                w2[u] = pkh(g2.x, g2.y);
            }
            F16U t;
            t.u = make_uint4(wh[0], wh[1], wh[2], wh[3]); Bf[0][kc] = t.v;
            t.u = make_uint4(w0[0], w0[1], w0[2], w0[3]); Bf[1][kc] = t.v;
            t.u = make_uint4(w1[0], w1[1], w1[2], w1[3]); Bf[2][kc] = t.v;
            t.u = make_uint4(w2[0], w2[1], w2[2], w2[3]); Bf[3][kc] = t.v;
        }

        // ---- MFMA + pair-packed epilogue; curl via +/- accumulators ----
        f32x2 cp0 = {0.f,0.f}, cp1 = cp0, cp2 = cp0;
        f32x2 cn0 = cp0, cn1 = cp0, cn2 = cp0;
#pragma unroll
        for (int m = 0; m < 4; ++m) {
            F16U A0, A1;
            const uint4* pA = &sA[(m * 2) * 64 + lane];
            A0.u = pA[0];
            A1.u = pA[64];

            AccU a0, a1, a2, a3;
            a0.v = (f32x4){0.f,0.f,0.f,0.f}; a1.v = a0.v; a2.v = a0.v; a3.v = a0.v;
            a0.v = MFMA(A0.v, Bf[0][0], a0.v, 0, 0, 0);
            a1.v = MFMA(A0.v, Bf[1][0], a1.v, 0, 0, 0);
            a2.v = MFMA(A0.v, Bf[2][0], a2.v, 0, 0, 0);
            a3.v = MFMA(A0.v, Bf[3][0], a3.v, 0, 0, 0);
            a0.v = MFMA(A1.v, Bf[0][1], a0.v, 0, 0, 0);
            a1.v = MFMA(A1.v, Bf[1][1], a1.v, 0, 0, 0);
            a2.v = MFMA(A1.v, Bf[2][1], a2.v, 0, 0, 0);
            a3.v = MFMA(A1.v, Bf[3][1], a3.v, 0, 0, 0);

            // Epilogue pairs rp: h = m*16 + q*4 + {2rp, 2rp+1}
#pragma unroll
            for (int rp = 0; rp < 2; ++rp) {
                PairU la, lb;
                la.f4 = sLUTa[m * 8 + q * 2 + rp];
                lb.f4 = sLUTb[m * 8 + q * 2 + rp];
                const f32x2 s0 = pk_add(a0.p[rp], la.p[0]);
                const f32x2 th = tanh2(s0, cst2, one2, ntwo2);
                const f32x2 t2 = pk_mul(th, th);
                const f32x2 d2 = pk_fma(t2, none2, one2);
                const f32x2 e0 = pk_mul(la.p[1], d2);
                const f32x2 e1 = pk_mul(lb.p[0], d2);
                const f32x2 e2 = pk_mul(lb.p[1], d2);
                // c0 += e2*u1 - e1*u2 ; c1 += e0*u2 - e2*u0 ; c2 += e1*u0 - e0*u1
                cp0 = pk_fma(e2, a2.p[rp], cp0);  cn0 = pk_fma(e1, a3.p[rp], cn0);
                cp1 = pk_fma(e0, a3.p[rp], cp1);  cn1 = pk_fma(e2, a1.p[rp], cn1);
                cp2 = pk_fma(e1, a1.p[rp], cp2);  cn2 = pk_fma(e0, a2.p[rp], cn2);
            }
        }

        float c0 = (cp0.x - cn0.x) + (cp0.y - cn0.y);
        float c1 = (cp1.x - cn1.x) + (cp1.y - cn1.y);
        float c2 = (cp2.x - cn2.x) + (cp2.y - cn2.y);

        // Reduce partial curls over the 4 h-subgroups (q dimension).
        c0 += __shfl_xor(c0, 16); c0 += __shfl_xor(c0, 32);
        c1 += __shfl_xor(c1, 16); c1 += __shfl_xor(c1, 32);
        c2 += __shfl_xor(c2, 16); c2 += __shfl_xor(c2, 32);

        // Coalesced store: lane (p,q<3) writes component q of point p.
        if (q < 3 && id < npts) {
            const float cv = (q == 0) ? c0 : ((q == 1) ? c1 : c2);
            out[tile * (NPT * 3) + p * 3 + q] = cv;
        }
    }
}

extern "C" void kernel_launch(void* const* d_in, const int* in_sizes, int n_in,
                              void* d_out, int out_size, void* d_ws, size_t ws_size,
                              hipStream_t stream) {
    const float* x  = (const float*)d_in[0];
    const float* W1 = (const float*)d_in[1];
    const float* b1 = (const float*)d_in[2];
    const float* W2 = (const float*)d_in[3];
    const float* b2 = (const float*)d_in[4];
    const float* W3 = (const float*)d_in[5];
    // d_in[6] (b3) unused: it cancels in the Jacobian.
    float* out = (float*)d_out;

    const int npts   = in_sizes[0] / 3;
    const int ntiles = (npts + NPT - 1) / NPT;
    int blocks = (ntiles + NWAVE - 1) / NWAVE;
    if (blocks > MAXB) blocks = MAXB;
    const int nw    = blocks * NWAVE;
    const int iters = (ntiles + nw - 1) / nw;

    hipLaunchKernelGGL(curl_mfma, dim3(blocks), dim3(BLK), 0, stream,
                       x, W1, b1, W2, b2, W3, out, npts, iters, ntiles);
}